// Round 8
// baseline (392.982 us; speedup 1.0000x reference)
//
#include <hip/hip_runtime.h>
#include <hip/hip_bf16.h>

// AttentiveGraph: B=4, N=10000, E=160000, C=F=128, 3 iterations.
// R18: edge kernel sits ~2x above its L1-line floor; pipelining exhausted ->
// hypothesis: per-CU outstanding-request-count x L2-latency is binding.
// Halve the request count at equal bytes:
//   gat merged into ONE array of 512B rows (128ch x u32 {S fp16|EL fp16});
//   each gather = one dwordx2/lane = 512B/wave = ALL 128 channels, ONE request
//   (was 2 x 256B across two half-arrays). Gathers 2.56M -> 1.28M/dispatch;
//   index loads + readfirstlane also halve (edge processed once).
// Wave parallelism kept via NODE-half split (n<5000 / n>=5000) instead of
// channel-half; XCD pinning kept (xcd = b*2+half). Producer phase2 writes the
// merged gat (same coalescing). Discriminating experiment: if L1-line
// throughput (not request count) is the wall, this is neutral.
// Everything else = R17 (355.9us best): scalar ping-pong gather, fma_mix,
// CSR pad-to-8 + sentinel rows, fused dispatches.

#define BATCH 4
#define NNODE 10000
#define NEDGE 160000
#define TWOE  (2*NEDGE)
#define MROWS (BATCH*NNODE)   // 40000
#define NCHUNK 64
#define CHUNKE (NEDGE/NCHUNK) // 2500
#define PADN  10240
#define EDPAD (TWOE + 8*NNODE) // 400000: padded edge capacity per batch

typedef unsigned short u16;
typedef unsigned int   u32;
typedef __attribute__((ext_vector_type(8))) short bf16x8_t;
typedef __attribute__((ext_vector_type(4))) float f32x4_t;

__device__ __forceinline__ float b2f(u16 h){ return __uint_as_float(((u32)h) << 16); }
__device__ __forceinline__ u16 f2bf(float f){
  u32 u = __float_as_uint(f);
  return (u16)((u + 0x7fffu + ((u >> 16) & 1u)) >> 16);   // RNE
}
__device__ __forceinline__ float fast_tanh(float x){
  float e = __expf(2.0f * x);
  return fmaf(-2.0f, __builtin_amdgcn_rcpf(e + 1.0f), 1.0f);
}

// ---------------- weights prep (with fused dtype probe) -----------------------
__global__ void prep_weights(const void* __restrict__ objects,
                             const void* __restrict__ Wo, const void* __restrict__ Wa,
                             const void* __restrict__ Wla, const void* __restrict__ Wl,
                             const void* __restrict__ ab, const void* __restrict__ sb,
                             int* __restrict__ flag, u16* __restrict__ Wt,
                             float* __restrict__ biasf){
  __shared__ int zc, hc;
  if (threadIdx.x == 0){ zc = 0; hc = 0; }
  __syncthreads();
  const u32* objw = (const u32*)objects;
  int z = 0, hcnt = 0;
  for (int i = threadIdx.x; i < 1024; i += 256){
    u32 lo = objw[i] & 0xffffu;
    if (lo == 0) z++;
    if (((lo >> 7) & 0xffu) >= 160u) hcnt++;
  }
  atomicAdd(&zc, z); atomicAdd(&hc, hcnt);
  __syncthreads();
  bool f = (hc > 0 || zc > 512);              // 1 = fp32 storage
  if (blockIdx.x == 0 && threadIdx.x == 0) *flag = f ? 1 : 0;

  int idx = blockIdx.x * 256 + threadIdx.x;
  if (idx < 65536){
    int m = idx >> 14, k = (idx >> 7) & 127, c = idx & 127;
    const void* src = (m == 0) ? Wo : (m == 1) ? Wa : (m == 2) ? Wla : Wl;
    u16 h = f ? f2bf(((const float*)src)[k * 128 + c]) : ((const u16*)src)[k * 128 + c];
    Wt[m * 16384 + c * 128 + k] = h;
  } else {
    int t = idx - 65536;
    const void* src = (t < 128) ? sb : ab;
    int i = t & 127;
    biasf[t] = f ? ((const float*)src)[i] : b2f(((const u16*)src)[i]);
  }
}

// ---------------- CSR build: 3-phase chunked histogram ------------------------
__device__ __forceinline__ void chunk_of(int blk, int& b, int& c){
  int xcd = blk & 7;
  b = xcd >> 1;
  c = ((blk >> 3) << 1) | (xcd & 1);           // 0..63
}

__global__ void __launch_bounds__(256) csr_hist(const int* __restrict__ conn,
                                                u16* __restrict__ partial){
  int b, c; chunk_of(blockIdx.x, b, c);
  __shared__ u32 hist[NNODE];
  for (int n = threadIdx.x; n < NNODE; n += 256) hist[n] = 0;
  __syncthreads();
  const int2* cp = (const int2*)conn + (size_t)b * NEDGE + c * CHUNKE;
  for (int i = threadIdx.x; i < CHUNKE; i += 256){
    int2 e = cp[i];
    atomicAdd(&hist[e.x], 1);
    atomicAdd(&hist[e.y], 1);
  }
  __syncthreads();
  u16* prow = partial + (size_t)(b * NCHUNK + c) * PADN;
  for (int n = threadIdx.x; n < NNODE; n += 256) prow[n] = (u16)hist[n];
}

__global__ void __launch_bounds__(256) csr_colscan(u16* __restrict__ partial,
    int* __restrict__ row_start, int* __restrict__ bsum, int* __restrict__ deg){
  int b = blockIdx.x / 40, w = blockIdx.x % 40;
  int n = w * 256 + threadIdx.x;
  u32 run = 0;
  if (n < NNODE){
    #pragma unroll 8
    for (int c = 0; c < NCHUNK; c++){
      size_t idx = (size_t)(b * NCHUNK + c) * PADN + n;
      u32 v = partial[idx];
      partial[idx] = (u16)run;
      run += v;
    }
  }
  u32 pad = (run + 7u) & ~7u;
  __shared__ u32 buf[256];
  buf[threadIdx.x] = pad;
  __syncthreads();
  for (int off = 1; off < 256; off <<= 1){
    u32 x = (threadIdx.x >= (unsigned)off) ? buf[threadIdx.x - off] : 0;
    __syncthreads();
    buf[threadIdx.x] += x;
    __syncthreads();
  }
  u32 incl = buf[threadIdx.x];
  if (n < NNODE){
    row_start[b * (NNODE + 1) + n] = (int)(incl - pad);  // window-local padded
    deg[b * NNODE + n] = (int)run;
  }
  if (threadIdx.x == 255) bsum[blockIdx.x] = (int)incl;
}

// scanC with scanB folded in.
__global__ void scanC(int* __restrict__ row_start, const int* __restrict__ bsum){
  int b = blockIdx.x / 40, j = blockIdx.x % 40;
  int n = j * 256 + threadIdx.x;
  int off = 0;
  for (int q = b * 40; q < b * 40 + j; q++) off += bsum[q];
  if (n < NNODE) row_start[b * (NNODE + 1) + n] += off;
  if (j == 39 && threadIdx.x == 0)
    row_start[b * (NNODE + 1) + NNODE] = off + bsum[b * 40 + 39];
}

__global__ void __launch_bounds__(256) csr_fill(const int* __restrict__ conn,
    const u16* __restrict__ partial, const int* __restrict__ row_start,
    int* __restrict__ edge_dst){
  int b, c; chunk_of(blockIdx.x, b, c);
  __shared__ u32 cur[NNODE];
  const u16* prow = partial + (size_t)(b * NCHUNK + c) * PADN;
  const int* rs = row_start + b * (NNODE + 1);
  for (int n = threadIdx.x; n < NNODE; n += 256) cur[n] = (u32)rs[n] + prow[n];
  __syncthreads();
  const int2* cp = (const int2*)conn + (size_t)b * NEDGE + c * CHUNKE;
  int* edb = edge_dst + (size_t)b * EDPAD;
  for (int i = threadIdx.x; i < CHUNKE; i += 256){
    int2 e = cp[i];
    u32 p1 = atomicAdd(&cur[e.x], 1); edb[p1] = e.y;
    u32 p2 = atomicAdd(&cur[e.y], 1); edb[p2] = e.x;
  }
}

// pad fill + sentinel-row zeroing (merged gat: rows 40000..40003, 512B each).
__global__ void pad_fill(const int* __restrict__ row_start,
                         const int* __restrict__ deg, int* __restrict__ edge_dst,
                         u32* __restrict__ gat){
  if (blockIdx.x == 0){
    size_t base = (size_t)MROWS * 128;
    gat[base + threadIdx.x]       = 0;
    gat[base + 256 + threadIdx.x] = 0;
  }
  int b = blockIdx.x / 40, j = blockIdx.x % 40;
  int n = j * 256 + threadIdx.x;
  if (n >= NNODE) return;
  const int* rs = row_start + b * (NNODE + 1);
  int s = rs[n] + deg[b * NNODE + n];
  int epad = rs[n + 1];
  int sent = 40000 - 9999 * b;     // local d -> global gat row 40000+b (zero)
  int* edb = edge_dst + (size_t)b * EDPAD;
  for (int p = s; p < epad; p++) edb[p] = sent;
}

// ---------------- MFMA helpers (wave = 16 rows x 64 cols) ---------------------
__device__ __forceinline__ void gemm_tile4(const u16* __restrict__ arow,
    const u16* __restrict__ wt, int lm, int lq, int cofs, f32x4_t acc[4]){
  #pragma unroll
  for (int ks = 0; ks < 4; ks++){
    bf16x8_t a = *(const bf16x8_t*)(arow + ks * 32);
    #pragma unroll
    for (int nb = 0; nb < 4; nb++){
      bf16x8_t bfr = *(const bf16x8_t*)(wt + (cofs + nb * 16 + lm) * 128 + ks * 32 + lq * 8);
      acc[nb] = __builtin_amdgcn_mfma_f32_16x16x32_bf16(a, bfr, acc[nb], 0, 0, 0);
    }
  }
}

__device__ __forceinline__ void gemm_tile4_packed(const u32* __restrict__ Lrow,
    const u16* __restrict__ wt, int lm, int lq, int cofs, f32x4_t acc[4]){
  #pragma unroll
  for (int ks = 0; ks < 4; ks++){
    uint4 wa = *(const uint4*)(Lrow + ks * 32 + lq * 8);
    uint4 wb = *(const uint4*)(Lrow + ks * 32 + lq * 8 + 4);
    bf16x8_t a;
    a[0] = (short)wa.x; a[1] = (short)wa.y; a[2] = (short)wa.z; a[3] = (short)wa.w;
    a[4] = (short)wb.x; a[5] = (short)wb.y; a[6] = (short)wb.z; a[7] = (short)wb.w;
    #pragma unroll
    for (int nb = 0; nb < 4; nb++){
      bf16x8_t bfr = *(const bf16x8_t*)(wt + (cofs + nb * 16 + lm) * 128 + ks * 32 + lq * 8);
      acc[nb] = __builtin_amdgcn_mfma_f32_16x16x32_bf16(a, bfr, acc[nb], 0, 0, 0);
    }
  }
}

// phase 2: states tile (LDS) -> merged gat {S fp16 hi | EL fp16 lo} u32 row
// stores + ea fp16 into LDS tile eat.
__device__ __forceinline__ void phase2_awlaw4(const u16* __restrict__ ldstile,
    const u16* __restrict__ Wt, const float* __restrict__ biasf,
    int lm, int lq, int cofs, int r0, _Float16* __restrict__ eat,
    u32* __restrict__ gat){
  const u16* Wta  = Wt + 16384;
  const u16* Wtla = Wt + 32768;
  const u16* ldsrow = ldstile + lm * 136 + lq * 8;
  f32x4_t accA[4], accL[4];
  #pragma unroll
  for (int i = 0; i < 4; i++){ accA[i] = (f32x4_t){0.f,0.f,0.f,0.f}; accL[i] = (f32x4_t){0.f,0.f,0.f,0.f}; }
  #pragma unroll
  for (int ks = 0; ks < 4; ks++){
    bf16x8_t a = *(const bf16x8_t*)(ldsrow + ks * 32);
    #pragma unroll
    for (int nb = 0; nb < 4; nb++){
      bf16x8_t ba = *(const bf16x8_t*)(Wta  + (cofs + nb * 16 + lm) * 128 + ks * 32 + lq * 8);
      bf16x8_t bl = *(const bf16x8_t*)(Wtla + (cofs + nb * 16 + lm) * 128 + ks * 32 + lq * 8);
      accA[nb] = __builtin_amdgcn_mfma_f32_16x16x32_bf16(a, ba, accA[nb], 0, 0, 0);
      accL[nb] = __builtin_amdgcn_mfma_f32_16x16x32_bf16(a, bl, accL[nb], 0, 0, 0);
    }
  }
  #pragma unroll
  for (int nb = 0; nb < 4; nb++){
    int col = cofs + nb * 16 + lm;
    float bb = biasf[128 + col];
    #pragma unroll
    for (int i = 0; i < 4; i++){
      int row = r0 + lq * 4 + i;
      float ea = fminf(__expf(accA[nb][i]), 60000.0f);   // fp16-safe
      eat[(lq * 4 + i) * 128 + col] = (_Float16)ea;
      _Float16 elh = (_Float16)fminf(__expf(accL[nb][i] + bb), 60000.0f);
      u16 sbf = ldstile[(lq * 4 + i) * 136 + col];
      _Float16 sh = (_Float16)b2f(sbf);                  // bf16 -> fp16 exact
      u32 elu = (u32)(*(const u16*)&elh);
      u32 shu = (u32)(*(const u16*)&sh);
      gat[(size_t)row * 128 + col] = elu | (shu << 16);
    }
  }
}

// coalesced eah writeback: 2 tiles x 16 rows x 128 fp16 = 8KB, 16B/thread x2.
__device__ __forceinline__ void eah_writeback(const _Float16* __restrict__ eat,
    _Float16* __restrict__ eah, int blk_r0, int tid){
  const uint4* src = (const uint4*)eat;       // 512 x 16B
  uint4* dst = (uint4*)(eah + (size_t)blk_r0 * 128);
  dst[tid]       = src[tid];
  dst[tid + 256] = src[tid + 256];
}

// init: states = tanh(obj@Wo + b) from raw objects; then eah/EL/S.
__global__ void __launch_bounds__(256) fused_init(const void* __restrict__ obj_raw,
    const int* __restrict__ flag, const u16* __restrict__ Wt,
    const float* __restrict__ biasf, _Float16* __restrict__ eah,
    u32* __restrict__ gat){
  __shared__ u16 lds[2][16 * 136];
  __shared__ _Float16 eat[2][16 * 128];
  const int lane = threadIdx.x & 63, wave = threadIdx.x >> 6;
  const int t = wave >> 1, ch = wave & 1, cofs = ch * 64;
  const int r0 = blockIdx.x * 32 + t * 16;
  const int lm = lane & 15, lq = lane >> 4;
  f32x4_t acc[4];
  #pragma unroll
  for (int i = 0; i < 4; i++) acc[i] = (f32x4_t){0.f, 0.f, 0.f, 0.f};
  if (*flag){
    const float* arow = (const float*)obj_raw + (size_t)(r0 + lm) * 128 + lq * 8;
    #pragma unroll
    for (int ks = 0; ks < 4; ks++){
      float4 fa = *(const float4*)(arow + ks * 32);
      float4 fb = *(const float4*)(arow + ks * 32 + 4);
      bf16x8_t a;
      a[0] = (short)f2bf(fa.x); a[1] = (short)f2bf(fa.y);
      a[2] = (short)f2bf(fa.z); a[3] = (short)f2bf(fa.w);
      a[4] = (short)f2bf(fb.x); a[5] = (short)f2bf(fb.y);
      a[6] = (short)f2bf(fb.z); a[7] = (short)f2bf(fb.w);
      #pragma unroll
      for (int nb = 0; nb < 4; nb++){
        bf16x8_t bfr = *(const bf16x8_t*)(Wt + (cofs + nb * 16 + lm) * 128 + ks * 32 + lq * 8);
        acc[nb] = __builtin_amdgcn_mfma_f32_16x16x32_bf16(a, bfr, acc[nb], 0, 0, 0);
      }
    }
  } else {
    gemm_tile4((const u16*)obj_raw + (size_t)(r0 + lm) * 128 + lq * 8, Wt, lm, lq, cofs, acc);
  }
  #pragma unroll
  for (int nb = 0; nb < 4; nb++){
    int col = cofs + nb * 16 + lm;
    float bb = biasf[col];
    #pragma unroll
    for (int i = 0; i < 4; i++)
      lds[t][(lq * 4 + i) * 136 + col] = f2bf(fast_tanh(acc[nb][i] + bb));
  }
  __syncthreads();
  phase2_awlaw4(&lds[t][0], Wt, biasf, lm, lq, cofs, r0, &eat[t][0], gat);
  __syncthreads();
  eah_writeback(&eat[0][0], eah, blockIdx.x * 32, threadIdx.x);
}

// mid: states = tanh(sa + lg@Wl + b); then eah/EL/S for next iter.
__global__ void __launch_bounds__(256) fused_mid(const u32* __restrict__ lgsa,
    const u16* __restrict__ Wt, const float* __restrict__ biasf,
    _Float16* __restrict__ eah, u32* __restrict__ gat){
  __shared__ u16 lds[2][16 * 136];
  __shared__ _Float16 eat[2][16 * 128];
  const int lane = threadIdx.x & 63, wave = threadIdx.x >> 6;
  const int t = wave >> 1, ch = wave & 1, cofs = ch * 64;
  const int r0 = blockIdx.x * 32 + t * 16;
  const int lm = lane & 15, lq = lane >> 4;
  f32x4_t acc[4];
  #pragma unroll
  for (int i = 0; i < 4; i++) acc[i] = (f32x4_t){0.f, 0.f, 0.f, 0.f};
  gemm_tile4_packed(lgsa + (size_t)(r0 + lm) * 128, Wt + 49152, lm, lq, cofs, acc);
  #pragma unroll
  for (int nb = 0; nb < 4; nb++){
    int col = cofs + nb * 16 + lm;
    float bb = biasf[col];
    #pragma unroll
    for (int i = 0; i < 4; i++){
      int row = r0 + lq * 4 + i;
      u32 v = lgsa[(size_t)row * 128 + col];
      u16 hb = (u16)(v >> 16);
      float sa = (float)(*(const _Float16*)&hb);
      lds[t][(lq * 4 + i) * 136 + col] = f2bf(fast_tanh(sa + acc[nb][i] + bb));
    }
  }
  __syncthreads();
  phase2_awlaw4(&lds[t][0], Wt, biasf, lm, lq, cofs, r0, &eat[t][0], gat);
  __syncthreads();
  eah_writeback(&eat[0][0], eah, blockIdx.x * 32, threadIdx.x);
}

// final: out = tanh(sa + lg@Wl + b), fp32 or bf16 per flag.
__global__ void __launch_bounds__(256) final_out(const u32* __restrict__ lgsa,
    const u16* __restrict__ Wt, const float* __restrict__ biasf,
    const int* __restrict__ flag, void* __restrict__ outp){
  const int lane = threadIdx.x & 63, wave = threadIdx.x >> 6;
  const int t = wave >> 1, ch = wave & 1, cofs = ch * 64;
  const int r0 = blockIdx.x * 32 + t * 16;
  const int lm = lane & 15, lq = lane >> 4;
  bool f32out = (*flag != 0);
  f32x4_t acc[4];
  #pragma unroll
  for (int i = 0; i < 4; i++) acc[i] = (f32x4_t){0.f, 0.f, 0.f, 0.f};
  gemm_tile4_packed(lgsa + (size_t)(r0 + lm) * 128, Wt + 49152, lm, lq, cofs, acc);
  #pragma unroll
  for (int nb = 0; nb < 4; nb++){
    int col = cofs + nb * 16 + lm;
    float bb = biasf[col];
    #pragma unroll
    for (int i = 0; i < 4; i++){
      int row = r0 + lq * 4 + i;
      u32 vv = lgsa[(size_t)row * 128 + col];
      u16 hb = (u16)(vv >> 16);
      float sa = (float)(*(const _Float16*)&hb);
      float v = fast_tanh(sa + acc[nb][i] + bb);
      if (f32out) ((float*)outp)[(size_t)row * 128 + col] = v;
      else        ((u16*)  outp)[(size_t)row * 128 + col] = f2bf(v);
    }
  }
}

// ---------------- edge gather: full 512B row per request ----------------------
// g = {S fp16 hi | EL fp16 lo}; lane c holds channels 2c (g.x) and 2c+1 (g.y).
// 2 fma_mix per (edge,u32), fp32 accum.
__device__ __forceinline__ void acc_mix(u32 g, float one, float& a1, float& a2){
  asm("v_fma_mix_f32 %0, %2, %3, %0 op_sel:[0,0,0] op_sel_hi:[1,0,0]\n\t"
      "v_fma_mix_f32 %1, %2, %2, %1 op_sel:[0,1,0] op_sel_hi:[1,1,0]"
      : "+v"(a1), "+v"(a2)
      : "v"(g), "v"(one));
}

// scalar-addressed dwordx2 gather: d uniform (SGPR) -> saddr global_load,
// vaddr = c*8 loop-invariant. One instr = 512B/wave = full gat row.
__device__ __forceinline__ uint2 gath2(const u32* __restrict__ gat, int d, int c){
  return *(const uint2*)((const char*)gat + ((size_t)(u32)d << 9) + ((size_t)(u32)(c << 3)));
}

#define ACC2(G, p) \
  acc_mix((G).x, one, (p) ? t1x : s1x, (p) ? t2x : s2x); \
  acc_mix((G).y, one, (p) ? t1y : s1y, (p) ? t2y : s2y);

__global__ void __launch_bounds__(128, 8) edge_kernel(const _Float16* __restrict__ eah,
    const u32* __restrict__ gat, const int* __restrict__ row_start,
    const int* __restrict__ edge_dst, u32* __restrict__ lgsa){
  int blk = blockIdx.x;
  int xcd = blk & 7;
  int b = xcd >> 1, hh = xcd & 1;            // hh = node half
  int i = blk >> 3;                          // 0..2499
  int n = hh * 5000 + i * 2 + (int)(threadIdx.x >> 6);
  int node = b * NNODE + n;
  int c = threadIdx.x & 63;                  // channel pair index (2c, 2c+1)
  const u32* gb = gat + (size_t)b * NNODE * 128;
  int e0 = __builtin_amdgcn_readfirstlane(row_start[b * (NNODE + 1) + n]);
  int e1 = __builtin_amdgcn_readfirstlane(row_start[b * (NNODE + 1) + n + 1]);
  const int* ed = edge_dst + (size_t)b * EDPAD;

  // independent loads issued before the gather pipeline
  u32 eav = ((const u32*)eah)[(size_t)node * 64 + c];          // fp16 {2c,2c+1}
  uint2 self = gath2(gb, n, c);
  const float one = 1.0f;

  float s1x=0.f, s2x=0.f, t1x=0.f, t2x=0.f;
  float s1y=0.f, s2y=0.f, t1y=0.f, t2y=0.f;
  int ng = (e1 - e0) >> 3;                   // rows padded: len % 8 == 0
  if (ng){
    int dB[8]; uint2 g[8], gn[8];
    int e = e0;
    // prologue: idx(g0) -> gather(g0) -> idx(g1)
    { const int* ep = ed + e;
      #pragma unroll
      for (int j = 0; j < 8; j++) dB[j] = __builtin_amdgcn_readfirstlane(ep[j]); }
    #pragma unroll
    for (int j = 0; j < 8; j++) g[j] = gath2(gb, dB[j], c);
    e += 8;
    { const int* ep = ed + e;                // overshoot-safe: within workspace
      #pragma unroll
      for (int j = 0; j < 8; j++) dB[j] = __builtin_amdgcn_readfirstlane(ep[j]); }
    e += 8;
    // steady state: 2 groups/iter ping-pong; gathers k+1 issued before
    // consuming k; indices one group ahead.
    int k = 1;
    for (; k + 1 < ng; k += 2){
      #pragma unroll
      for (int j = 0; j < 8; j++) gn[j] = gath2(gb, dB[j], c);
      { const int* ep = ed + e;
        #pragma unroll
        for (int j = 0; j < 8; j++) dB[j] = __builtin_amdgcn_readfirstlane(ep[j]); }
      e += 8;
      #pragma unroll
      for (int j = 0; j < 8; j++){ ACC2(g[j], j & 1); }
      #pragma unroll
      for (int j = 0; j < 8; j++) g[j] = gath2(gb, dB[j], c);
      { const int* ep = ed + e;
        #pragma unroll
        for (int j = 0; j < 8; j++) dB[j] = __builtin_amdgcn_readfirstlane(ep[j]); }
      e += 8;
      #pragma unroll
      for (int j = 0; j < 8; j++){ ACC2(gn[j], j & 1); }
    }
    if (k < ng){                              // one trailing group in dB
      #pragma unroll
      for (int j = 0; j < 8; j++) gn[j] = gath2(gb, dB[j], c);
      #pragma unroll
      for (int j = 0; j < 8; j++){ ACC2(g[j], j & 1); }
      #pragma unroll
      for (int j = 0; j < 8; j++){ ACC2(gn[j], j & 1); }
    } else {
      #pragma unroll
      for (int j = 0; j < 8; j++){ ACC2(g[j], j & 1); }
    }
  }

  s1x += t1x; s2x += t2x; s1y += t1y; s2y += t2y;
  // finalize both channels; coalesced dwordx2 store (512B/wave)
  union { u32 u; _Float16 f[2]; } ec; ec.u = eav;
  u32 out[2];
  float S1[2] = {s1x, s1y};
  float S2[2] = {s2x, s2y};
  u32 SV[2] = {self.x, self.y};
  #pragma unroll
  for (int k2 = 0; k2 < 2; k2++){
    float ea = (float)ec.f[k2];
    float inv = __builtin_amdgcn_rcpf(fmaf(ea, S1[k2], 1.0f));
    float lg = ea * S2[k2] * inv;
    u16 hb = (u16)(SV[k2] >> 16);
    float s_self = (float)(*(const _Float16*)&hb);
    _Float16 hs = (_Float16)(s_self * inv);
    out[k2] = (u32)f2bf(lg) | ((u32)(*(const u16*)&hs) << 16);
  }
  *(uint2*)(lgsa + (size_t)node * 128 + (c << 1)) = *(const uint2*)out;
}

// ---------------- host launcher ----------------------------------------------
extern "C" void kernel_launch(void* const* d_in, const int* in_sizes, int n_in,
                              void* d_out, int out_size, void* d_ws, size_t ws_size,
                              hipStream_t stream){
  (void)in_sizes; (void)n_in; (void)ws_size; (void)out_size;
  const void* objects = d_in[0];
  const void* Wo      = d_in[1];
  const void* Wa      = d_in[2];
  const void* Wla     = d_in[3];
  const void* attn_b  = d_in[4];
  const void* Wl      = d_in[5];
  const void* state_b = d_in[6];
  const int*  conn    = (const int*)d_in[7];

  char* base = (char*)d_ws;
  size_t off = 0;
  auto alloc = [&](size_t bytes) -> char* {
    char* p = base + off;
    off = (off + bytes + 255) & ~(size_t)255;
    return p;
  };
  int*      flag      = (int*)     alloc(256);
  u16*      Wt        = (u16*)     alloc((size_t)4 * 16384 * 2);
  float*    biasf     = (float*)   alloc(256 * 4);
  _Float16* eah       = (_Float16*)alloc((size_t)MROWS * 128 * 2);        // exp(aW) fp16
  u32*      gat       = (u32*)     alloc((size_t)(MROWS + 4) * 128 * 4);  // 512B rows + 4 zero rows
  u32*      lgsa      = (u32*)     alloc((size_t)MROWS * 128 * 4);        // {lg bf16 | sa fp16}
  u16*      partial   = (u16*)     alloc((size_t)BATCH * NCHUNK * PADN * 2);
  int*      row_start = (int*)     alloc((size_t)BATCH * (NNODE + 1) * 4);
  int*      edge_dst  = (int*)     alloc((size_t)BATCH * EDPAD * 4);      // padded CSR
  int*      deg       = (int*)     alloc((size_t)MROWS * 4);
  int*      bsum      = (int*)     alloc(160 * 4);

  prep_weights<<<257, 256, 0, stream>>>(objects, Wo, Wa, Wla, Wl, attn_b, state_b,
                                        flag, Wt, biasf);

  csr_hist<<<256, 256, 0, stream>>>(conn, partial);
  csr_colscan<<<160, 256, 0, stream>>>(partial, row_start, bsum, deg);
  scanC<<<160, 256, 0, stream>>>(row_start, bsum);
  csr_fill<<<256, 256, 0, stream>>>(conn, partial, row_start, edge_dst);
  pad_fill<<<160, 256, 0, stream>>>(row_start, deg, edge_dst, gat);

  fused_init<<<MROWS / 32, 256, 0, stream>>>(objects, flag, Wt, biasf, eah, gat);
  edge_kernel<<<MROWS / 2, 128, 0, stream>>>(eah, gat, row_start, edge_dst, lgsa);
  fused_mid<<<MROWS / 32, 256, 0, stream>>>(lgsa, Wt, biasf, eah, gat);
  edge_kernel<<<MROWS / 2, 128, 0, stream>>>(eah, gat, row_start, edge_dst, lgsa);
  fused_mid<<<MROWS / 32, 256, 0, stream>>>(lgsa, Wt, biasf, eah, gat);
  edge_kernel<<<MROWS / 2, 128, 0, stream>>>(eah, gat, row_start, edge_dst, lgsa);
  final_out<<<MROWS / 32, 256, 0, stream>>>(lgsa, Wt, biasf, flag, d_out);
}

// Round 10
// 356.211 us; speedup vs baseline: 1.1032x; 1.1032x over previous
//
#include <hip/hip_runtime.h>
#include <hip/hip_bf16.h>

// AttentiveGraph: B=4, N=10000, E=160000, C=F=128, 3 iterations.
// R20 = R19 + crash fix. R19's paired steady loop gathers group m for the
// shorter chain using indices read past the chain end; for batch-final nodes
// those ed[] positions were UNINITIALIZED ([T,EDPAD) tail) -> garbage gather
// index -> OOB -> GPU fault. Fix: pad_fill also fills each batch's
// [T, EDPAD) tail with the sentinel index, so every over-read index group
// resolves to the zero gat row (safe no-op gather). Hot loop unchanged.
// R19 design: TWO independent node-chains per wave (paired 2x ping-pong,
// 32 gathers in flight), L2-resident channel-half gat (R18 proved residency
// binds), scalar saddr gathers, fma_mix, CSR pad-to-8 + sentinel rows.

#define BATCH 4
#define NNODE 10000
#define NEDGE 160000
#define TWOE  (2*NEDGE)
#define MROWS (BATCH*NNODE)   // 40000
#define NCHUNK 64
#define CHUNKE (NEDGE/NCHUNK) // 2500
#define PADN  10240
#define EDPAD (TWOE + 8*NNODE) // 400000: padded edge capacity per batch

typedef unsigned short u16;
typedef unsigned int   u32;
typedef __attribute__((ext_vector_type(8))) short bf16x8_t;
typedef __attribute__((ext_vector_type(4))) float f32x4_t;

__device__ __forceinline__ float b2f(u16 h){ return __uint_as_float(((u32)h) << 16); }
__device__ __forceinline__ u16 f2bf(float f){
  u32 u = __float_as_uint(f);
  return (u16)((u + 0x7fffu + ((u >> 16) & 1u)) >> 16);   // RNE
}
__device__ __forceinline__ float fast_tanh(float x){
  float e = __expf(2.0f * x);
  return fmaf(-2.0f, __builtin_amdgcn_rcpf(e + 1.0f), 1.0f);
}

// ---------------- weights prep (with fused dtype probe) -----------------------
__global__ void prep_weights(const void* __restrict__ objects,
                             const void* __restrict__ Wo, const void* __restrict__ Wa,
                             const void* __restrict__ Wla, const void* __restrict__ Wl,
                             const void* __restrict__ ab, const void* __restrict__ sb,
                             int* __restrict__ flag, u16* __restrict__ Wt,
                             float* __restrict__ biasf){
  __shared__ int zc, hc;
  if (threadIdx.x == 0){ zc = 0; hc = 0; }
  __syncthreads();
  const u32* objw = (const u32*)objects;
  int z = 0, hcnt = 0;
  for (int i = threadIdx.x; i < 1024; i += 256){
    u32 lo = objw[i] & 0xffffu;
    if (lo == 0) z++;
    if (((lo >> 7) & 0xffu) >= 160u) hcnt++;
  }
  atomicAdd(&zc, z); atomicAdd(&hc, hcnt);
  __syncthreads();
  bool f = (hc > 0 || zc > 512);              // 1 = fp32 storage
  if (blockIdx.x == 0 && threadIdx.x == 0) *flag = f ? 1 : 0;

  int idx = blockIdx.x * 256 + threadIdx.x;
  if (idx < 65536){
    int m = idx >> 14, k = (idx >> 7) & 127, c = idx & 127;
    const void* src = (m == 0) ? Wo : (m == 1) ? Wa : (m == 2) ? Wla : Wl;
    u16 h = f ? f2bf(((const float*)src)[k * 128 + c]) : ((const u16*)src)[k * 128 + c];
    Wt[m * 16384 + c * 128 + k] = h;
  } else {
    int t = idx - 65536;
    const void* src = (t < 128) ? sb : ab;
    int i = t & 127;
    biasf[t] = f ? ((const float*)src)[i] : b2f(((const u16*)src)[i]);
  }
}

// ---------------- CSR build: 3-phase chunked histogram ------------------------
__device__ __forceinline__ void chunk_of(int blk, int& b, int& c){
  int xcd = blk & 7;
  b = xcd >> 1;
  c = ((blk >> 3) << 1) | (xcd & 1);           // 0..63
}

__global__ void __launch_bounds__(256) csr_hist(const int* __restrict__ conn,
                                                u16* __restrict__ partial){
  int b, c; chunk_of(blockIdx.x, b, c);
  __shared__ u32 hist[NNODE];
  for (int n = threadIdx.x; n < NNODE; n += 256) hist[n] = 0;
  __syncthreads();
  const int2* cp = (const int2*)conn + (size_t)b * NEDGE + c * CHUNKE;
  for (int i = threadIdx.x; i < CHUNKE; i += 256){
    int2 e = cp[i];
    atomicAdd(&hist[e.x], 1);
    atomicAdd(&hist[e.y], 1);
  }
  __syncthreads();
  u16* prow = partial + (size_t)(b * NCHUNK + c) * PADN;
  for (int n = threadIdx.x; n < NNODE; n += 256) prow[n] = (u16)hist[n];
}

__global__ void __launch_bounds__(256) csr_colscan(u16* __restrict__ partial,
    int* __restrict__ row_start, int* __restrict__ bsum, int* __restrict__ deg){
  int b = blockIdx.x / 40, w = blockIdx.x % 40;
  int n = w * 256 + threadIdx.x;
  u32 run = 0;
  if (n < NNODE){
    #pragma unroll 8
    for (int c = 0; c < NCHUNK; c++){
      size_t idx = (size_t)(b * NCHUNK + c) * PADN + n;
      u32 v = partial[idx];
      partial[idx] = (u16)run;
      run += v;
    }
  }
  u32 pad = (run + 7u) & ~7u;
  __shared__ u32 buf[256];
  buf[threadIdx.x] = pad;
  __syncthreads();
  for (int off = 1; off < 256; off <<= 1){
    u32 x = (threadIdx.x >= (unsigned)off) ? buf[threadIdx.x - off] : 0;
    __syncthreads();
    buf[threadIdx.x] += x;
    __syncthreads();
  }
  u32 incl = buf[threadIdx.x];
  if (n < NNODE){
    row_start[b * (NNODE + 1) + n] = (int)(incl - pad);  // window-local padded
    deg[b * NNODE + n] = (int)run;
  }
  if (threadIdx.x == 255) bsum[blockIdx.x] = (int)incl;
}

// scanC with scanB folded in.
__global__ void scanC(int* __restrict__ row_start, const int* __restrict__ bsum){
  int b = blockIdx.x / 40, j = blockIdx.x % 40;
  int n = j * 256 + threadIdx.x;
  int off = 0;
  for (int q = b * 40; q < b * 40 + j; q++) off += bsum[q];
  if (n < NNODE) row_start[b * (NNODE + 1) + n] += off;
  if (j == 39 && threadIdx.x == 0)
    row_start[b * (NNODE + 1) + NNODE] = off + bsum[b * 40 + 39];
}

__global__ void __launch_bounds__(256) csr_fill(const int* __restrict__ conn,
    const u16* __restrict__ partial, const int* __restrict__ row_start,
    int* __restrict__ edge_dst){
  int b, c; chunk_of(blockIdx.x, b, c);
  __shared__ u32 cur[NNODE];
  const u16* prow = partial + (size_t)(b * NCHUNK + c) * PADN;
  const int* rs = row_start + b * (NNODE + 1);
  for (int n = threadIdx.x; n < NNODE; n += 256) cur[n] = (u32)rs[n] + prow[n];
  __syncthreads();
  const int2* cp = (const int2*)conn + (size_t)b * NEDGE + c * CHUNKE;
  int* edb = edge_dst + (size_t)b * EDPAD;
  for (int i = threadIdx.x; i < CHUNKE; i += 256){
    int2 e = cp[i];
    u32 p1 = atomicAdd(&cur[e.x], 1); edb[p1] = e.y;
    u32 p2 = atomicAdd(&cur[e.y], 1); edb[p2] = e.x;
  }
}

// pad fill + sentinel-row zeroing + batch-tail fill (R20 crash fix):
// [rs[n]+deg, rs[n+1]) per node AND [T, EDPAD) per batch get the sentinel,
// so ANY over-read index group resolves to the zero gat row.
__global__ void pad_fill(const int* __restrict__ row_start,
                         const int* __restrict__ deg, int* __restrict__ edge_dst,
                         u32* __restrict__ g0, u32* __restrict__ g1){
  if (blockIdx.x == 0){
    size_t base = (size_t)MROWS * 64;
    g0[base + threadIdx.x] = 0;
    g1[base + threadIdx.x] = 0;
  }
  int b = blockIdx.x / 40, j = blockIdx.x % 40;
  const int* rs = row_start + b * (NNODE + 1);
  int sent = 40000 - 9999 * b;     // local d -> global gat row 40000+b (zero)
  int* edb = edge_dst + (size_t)b * EDPAD;
  if (j == 0){                      // fill uninitialized batch tail
    int T = rs[NNODE];
    for (int p = T + (int)threadIdx.x; p < EDPAD; p += 256) edb[p] = sent;
  }
  int n = j * 256 + threadIdx.x;
  if (n >= NNODE) return;
  int s = rs[n] + deg[b * NNODE + n];
  int epad = rs[n + 1];
  for (int p = s; p < epad; p++) edb[p] = sent;
}

// ---------------- MFMA helpers (wave = 16 rows x 64 cols) ---------------------
__device__ __forceinline__ void gemm_tile4(const u16* __restrict__ arow,
    const u16* __restrict__ wt, int lm, int lq, int cofs, f32x4_t acc[4]){
  #pragma unroll
  for (int ks = 0; ks < 4; ks++){
    bf16x8_t a = *(const bf16x8_t*)(arow + ks * 32);
    #pragma unroll
    for (int nb = 0; nb < 4; nb++){
      bf16x8_t bfr = *(const bf16x8_t*)(wt + (cofs + nb * 16 + lm) * 128 + ks * 32 + lq * 8);
      acc[nb] = __builtin_amdgcn_mfma_f32_16x16x32_bf16(a, bfr, acc[nb], 0, 0, 0);
    }
  }
}

__device__ __forceinline__ void gemm_tile4_packed(const u32* __restrict__ Lrow,
    const u16* __restrict__ wt, int lm, int lq, int cofs, f32x4_t acc[4]){
  #pragma unroll
  for (int ks = 0; ks < 4; ks++){
    uint4 wa = *(const uint4*)(Lrow + ks * 32 + lq * 8);
    uint4 wb = *(const uint4*)(Lrow + ks * 32 + lq * 8 + 4);
    bf16x8_t a;
    a[0] = (short)wa.x; a[1] = (short)wa.y; a[2] = (short)wa.z; a[3] = (short)wa.w;
    a[4] = (short)wb.x; a[5] = (short)wb.y; a[6] = (short)wb.z; a[7] = (short)wb.w;
    #pragma unroll
    for (int nb = 0; nb < 4; nb++){
      bf16x8_t bfr = *(const bf16x8_t*)(wt + (cofs + nb * 16 + lm) * 128 + ks * 32 + lq * 8);
      acc[nb] = __builtin_amdgcn_mfma_f32_16x16x32_bf16(a, bfr, acc[nb], 0, 0, 0);
    }
  }
}

// phase 2: states tile (LDS) -> gat {S fp16 hi | EL fp16 lo} u32 stores +
// ea fp16 into LDS tile eat.
__device__ __forceinline__ void phase2_awlaw4(const u16* __restrict__ ldstile,
    const u16* __restrict__ Wt, const float* __restrict__ biasf,
    int lm, int lq, int cofs, int r0, _Float16* __restrict__ eat,
    u32* __restrict__ ghw){
  const u16* Wta  = Wt + 16384;
  const u16* Wtla = Wt + 32768;
  const u16* ldsrow = ldstile + lm * 136 + lq * 8;
  f32x4_t accA[4], accL[4];
  #pragma unroll
  for (int i = 0; i < 4; i++){ accA[i] = (f32x4_t){0.f,0.f,0.f,0.f}; accL[i] = (f32x4_t){0.f,0.f,0.f,0.f}; }
  #pragma unroll
  for (int ks = 0; ks < 4; ks++){
    bf16x8_t a = *(const bf16x8_t*)(ldsrow + ks * 32);
    #pragma unroll
    for (int nb = 0; nb < 4; nb++){
      bf16x8_t ba = *(const bf16x8_t*)(Wta  + (cofs + nb * 16 + lm) * 128 + ks * 32 + lq * 8);
      bf16x8_t bl = *(const bf16x8_t*)(Wtla + (cofs + nb * 16 + lm) * 128 + ks * 32 + lq * 8);
      accA[nb] = __builtin_amdgcn_mfma_f32_16x16x32_bf16(a, ba, accA[nb], 0, 0, 0);
      accL[nb] = __builtin_amdgcn_mfma_f32_16x16x32_bf16(a, bl, accL[nb], 0, 0, 0);
    }
  }
  #pragma unroll
  for (int nb = 0; nb < 4; nb++){
    int col = cofs + nb * 16 + lm;
    float bb = biasf[128 + col];
    #pragma unroll
    for (int i = 0; i < 4; i++){
      int row = r0 + lq * 4 + i;
      float ea = fminf(__expf(accA[nb][i]), 60000.0f);   // fp16-safe
      eat[(lq * 4 + i) * 128 + col] = (_Float16)ea;
      _Float16 elh = (_Float16)fminf(__expf(accL[nb][i] + bb), 60000.0f);
      u16 sbf = ldstile[(lq * 4 + i) * 136 + col];
      _Float16 sh = (_Float16)b2f(sbf);                  // bf16 -> fp16 exact
      u32 elu = (u32)(*(const u16*)&elh);
      u32 shu = (u32)(*(const u16*)&sh);
      ghw[(size_t)row * 64 + (col & 63)] = elu | (shu << 16);
    }
  }
}

// coalesced eah writeback: 2 tiles x 16 rows x 128 fp16 = 8KB, 16B/thread x2.
__device__ __forceinline__ void eah_writeback(const _Float16* __restrict__ eat,
    _Float16* __restrict__ eah, int blk_r0, int tid){
  const uint4* src = (const uint4*)eat;       // 512 x 16B
  uint4* dst = (uint4*)(eah + (size_t)blk_r0 * 128);
  dst[tid]       = src[tid];
  dst[tid + 256] = src[tid + 256];
}

// init: states = tanh(obj@Wo + b) from raw objects; then eah/EL/S.
__global__ void __launch_bounds__(256) fused_init(const void* __restrict__ obj_raw,
    const int* __restrict__ flag, const u16* __restrict__ Wt,
    const float* __restrict__ biasf, _Float16* __restrict__ eah,
    u32* __restrict__ gat0, u32* __restrict__ gat1){
  __shared__ u16 lds[2][16 * 136];
  __shared__ _Float16 eat[2][16 * 128];
  const int lane = threadIdx.x & 63, wave = threadIdx.x >> 6;
  const int t = wave >> 1, ch = wave & 1, cofs = ch * 64;
  const int r0 = blockIdx.x * 32 + t * 16;
  const int lm = lane & 15, lq = lane >> 4;
  f32x4_t acc[4];
  #pragma unroll
  for (int i = 0; i < 4; i++) acc[i] = (f32x4_t){0.f, 0.f, 0.f, 0.f};
  if (*flag){
    const float* arow = (const float*)obj_raw + (size_t)(r0 + lm) * 128 + lq * 8;
    #pragma unroll
    for (int ks = 0; ks < 4; ks++){
      float4 fa = *(const float4*)(arow + ks * 32);
      float4 fb = *(const float4*)(arow + ks * 32 + 4);
      bf16x8_t a;
      a[0] = (short)f2bf(fa.x); a[1] = (short)f2bf(fa.y);
      a[2] = (short)f2bf(fa.z); a[3] = (short)f2bf(fa.w);
      a[4] = (short)f2bf(fb.x); a[5] = (short)f2bf(fb.y);
      a[6] = (short)f2bf(fb.z); a[7] = (short)f2bf(fb.w);
      #pragma unroll
      for (int nb = 0; nb < 4; nb++){
        bf16x8_t bfr = *(const bf16x8_t*)(Wt + (cofs + nb * 16 + lm) * 128 + ks * 32 + lq * 8);
        acc[nb] = __builtin_amdgcn_mfma_f32_16x16x32_bf16(a, bfr, acc[nb], 0, 0, 0);
      }
    }
  } else {
    gemm_tile4((const u16*)obj_raw + (size_t)(r0 + lm) * 128 + lq * 8, Wt, lm, lq, cofs, acc);
  }
  #pragma unroll
  for (int nb = 0; nb < 4; nb++){
    int col = cofs + nb * 16 + lm;
    float bb = biasf[col];
    #pragma unroll
    for (int i = 0; i < 4; i++)
      lds[t][(lq * 4 + i) * 136 + col] = f2bf(fast_tanh(acc[nb][i] + bb));
  }
  __syncthreads();
  phase2_awlaw4(&lds[t][0], Wt, biasf, lm, lq, cofs, r0, &eat[t][0], ch ? gat1 : gat0);
  __syncthreads();
  eah_writeback(&eat[0][0], eah, blockIdx.x * 32, threadIdx.x);
}

// mid: states = tanh(sa + lg@Wl + b); then eah/EL/S for next iter.
__global__ void __launch_bounds__(256) fused_mid(const u32* __restrict__ lgsa,
    const u16* __restrict__ Wt, const float* __restrict__ biasf,
    _Float16* __restrict__ eah, u32* __restrict__ gat0, u32* __restrict__ gat1){
  __shared__ u16 lds[2][16 * 136];
  __shared__ _Float16 eat[2][16 * 128];
  const int lane = threadIdx.x & 63, wave = threadIdx.x >> 6;
  const int t = wave >> 1, ch = wave & 1, cofs = ch * 64;
  const int r0 = blockIdx.x * 32 + t * 16;
  const int lm = lane & 15, lq = lane >> 4;
  f32x4_t acc[4];
  #pragma unroll
  for (int i = 0; i < 4; i++) acc[i] = (f32x4_t){0.f, 0.f, 0.f, 0.f};
  gemm_tile4_packed(lgsa + (size_t)(r0 + lm) * 128, Wt + 49152, lm, lq, cofs, acc);
  #pragma unroll
  for (int nb = 0; nb < 4; nb++){
    int col = cofs + nb * 16 + lm;
    float bb = biasf[col];
    #pragma unroll
    for (int i = 0; i < 4; i++){
      int row = r0 + lq * 4 + i;
      u32 v = lgsa[(size_t)row * 128 + col];
      u16 hb = (u16)(v >> 16);
      float sa = (float)(*(const _Float16*)&hb);
      lds[t][(lq * 4 + i) * 136 + col] = f2bf(fast_tanh(sa + acc[nb][i] + bb));
    }
  }
  __syncthreads();
  phase2_awlaw4(&lds[t][0], Wt, biasf, lm, lq, cofs, r0, &eat[t][0], ch ? gat1 : gat0);
  __syncthreads();
  eah_writeback(&eat[0][0], eah, blockIdx.x * 32, threadIdx.x);
}

// final: out = tanh(sa + lg@Wl + b), fp32 or bf16 per flag.
__global__ void __launch_bounds__(256) final_out(const u32* __restrict__ lgsa,
    const u16* __restrict__ Wt, const float* __restrict__ biasf,
    const int* __restrict__ flag, void* __restrict__ outp){
  const int lane = threadIdx.x & 63, wave = threadIdx.x >> 6;
  const int t = wave >> 1, ch = wave & 1, cofs = ch * 64;
  const int r0 = blockIdx.x * 32 + t * 16;
  const int lm = lane & 15, lq = lane >> 4;
  bool f32out = (*flag != 0);
  f32x4_t acc[4];
  #pragma unroll
  for (int i = 0; i < 4; i++) acc[i] = (f32x4_t){0.f, 0.f, 0.f, 0.f};
  gemm_tile4_packed(lgsa + (size_t)(r0 + lm) * 128, Wt + 49152, lm, lq, cofs, acc);
  #pragma unroll
  for (int nb = 0; nb < 4; nb++){
    int col = cofs + nb * 16 + lm;
    float bb = biasf[col];
    #pragma unroll
    for (int i = 0; i < 4; i++){
      int row = r0 + lq * 4 + i;
      u32 vv = lgsa[(size_t)row * 128 + col];
      u16 hb = (u16)(vv >> 16);
      float sa = (float)(*(const _Float16*)&hb);
      float v = fast_tanh(sa + acc[nb][i] + bb);
      if (f32out) ((float*)outp)[(size_t)row * 128 + col] = v;
      else        ((u16*)  outp)[(size_t)row * 128 + col] = f2bf(v);
    }
  }
}

// ---------------- edge gather: 2 node-chains per wave -------------------------
// g = {S fp16 hi | EL fp16 lo}. Exactly 2 VALU ops per edge:
//   a1 = f16lo(g)*one + a1 ; a2 = f16lo(g)*f16hi(g) + a2  (fp32 accum)
__device__ __forceinline__ void acc_mix(u32 g, float one, float& a1, float& a2){
  asm("v_fma_mix_f32 %0, %2, %3, %0 op_sel:[0,0,0] op_sel_hi:[1,0,0]\n\t"
      "v_fma_mix_f32 %1, %2, %2, %1 op_sel:[0,1,0] op_sel_hi:[1,1,0]"
      : "+v"(a1), "+v"(a2)
      : "v"(g), "v"(one));
}

// scalar-addressed gather: d uniform (SGPR) -> saddr-form global_load.
__device__ __forceinline__ u32 gath1(const u32* __restrict__ gh, int d, int c){
  const u32* p = (const u32*)((const char*)gh + ((size_t)(u32)d << 8));
  return p[c];
}

#define LDIDX(d, p) { const int* ep_ = (p); _Pragma("unroll") \
  for (int j = 0; j < 8; j++) d[j] = __builtin_amdgcn_readfirstlane(ep_[j]); }
#define GATH8(g, d) { _Pragma("unroll") \
  for (int j = 0; j < 8; j++) g[j] = gath1(gh, d[j], c); }
#define CONS8(g, s1, s2, t1, t2) { _Pragma("unroll") \
  for (int j = 0; j < 8; j++) acc_mix(g[j], one, (j & 1) ? t1 : s1, (j & 1) ? t2 : s2); }

__global__ void __launch_bounds__(128, 6) edge_kernel(const _Float16* __restrict__ eah,
    const u32* __restrict__ gat0, const u32* __restrict__ gat1,
    const int* __restrict__ row_start, const int* __restrict__ edge_dst,
    u32* __restrict__ lgsa){
  int blk = blockIdx.x;
  int xcd = blk & 7;
  int b = xcd >> 1, h = xcd & 1;
  int i = blk >> 3;                          // 0..2499
  int w = (int)(threadIdx.x >> 6);
  int nA = i * 4 + w * 2, nB = nA + 1;
  int c = threadIdx.x & 63;
  const u32* gh = (h ? gat1 : gat0) + (size_t)b * NNODE * 64;
  const int* rs = row_start + b * (NNODE + 1);
  int eA  = __builtin_amdgcn_readfirstlane(rs[nA]);
  int eA1 = __builtin_amdgcn_readfirstlane(rs[nA + 1]);
  int eB1 = __builtin_amdgcn_readfirstlane(rs[nB + 1]);
  int eB = eA1;
  const int* ed = edge_dst + (size_t)b * EDPAD;

  // independent loads issued before the gather pipeline
  float eaA = (float)eah[(size_t)(b * NNODE + nA) * 128 + h * 64 + c];
  float eaB = (float)eah[(size_t)(b * NNODE + nB) * 128 + h * 64 + c];
  u32 selfA = gh[((size_t)nA << 6) + c];
  u32 selfB = gh[((size_t)nB << 6) + c];
  const float one = 1.0f;

  float sA1=0.f, sA2=0.f, tA1=0.f, tA2=0.f;
  float sB1=0.f, sB2=0.f, tB1=0.f, tB2=0.f;
  int ngA = (eA1 - eA) >> 3, ngB = (eB1 - eB) >> 3;  // rows padded: len%8==0
  int dA[8], dB[8]; u32 gA[8], gB[8], hA[8], hB[8];

  // prologue: prime both chains (g = grp0, d = idx of grp1)
  if (ngA){ LDIDX(dA, ed + eA); }
  if (ngB){ LDIDX(dB, ed + eB); }
  if (ngA){ GATH8(gA, dA); eA += 8; LDIDX(dA, ed + eA); }
  if (ngB){ GATH8(gB, dB); eB += 8; LDIDX(dB, ed + eB); }

  // paired steady state: 2 groups per chain per iteration; up to 32 gathers
  // in flight across 2 independent chains. Over-read index groups resolve to
  // the sentinel (tail-filled) -> zero row -> safe.
  int m = ngA < ngB ? ngA : ngB;
  int cons = 0;
  for (; cons + 2 <= m; cons += 2){
    GATH8(hA, dA); eA += 8; LDIDX(dA, ed + eA);
    GATH8(hB, dB); eB += 8; LDIDX(dB, ed + eB);
    CONS8(gA, sA1, sA2, tA1, tA2);
    CONS8(gB, sB1, sB2, tB1, tB2);
    GATH8(gA, dA); eA += 8; LDIDX(dA, ed + eA);
    GATH8(gB, dB); eB += 8; LDIDX(dB, ed + eB);
    CONS8(hA, sA1, sA2, tA1, tA2);
    CONS8(hB, sB1, sB2, tB1, tB2);
  }

  // finish chain A (invariant: gA = grp(cons) if cons<ngA, dA = next idx)
  { int rem = ngA - cons;
    if (rem > 0){
      int k = 1;
      for (; k + 1 < rem; k += 2){
        GATH8(hA, dA); eA += 8; LDIDX(dA, ed + eA);
        CONS8(gA, sA1, sA2, tA1, tA2);
        GATH8(gA, dA); eA += 8; LDIDX(dA, ed + eA);
        CONS8(hA, sA1, sA2, tA1, tA2);
      }
      if (k < rem){
        GATH8(hA, dA);
        CONS8(gA, sA1, sA2, tA1, tA2);
        CONS8(hA, sA1, sA2, tA1, tA2);
      } else {
        CONS8(gA, sA1, sA2, tA1, tA2);
      }
    }
  }
  // finish chain B
  { int rem = ngB - cons;
    if (rem > 0){
      int k = 1;
      for (; k + 1 < rem; k += 2){
        GATH8(hB, dB); eB += 8; LDIDX(dB, ed + eB);
        CONS8(gB, sB1, sB2, tB1, tB2);
        GATH8(gB, dB); eB += 8; LDIDX(dB, ed + eB);
        CONS8(hB, sB1, sB2, tB1, tB2);
      }
      if (k < rem){
        GATH8(hB, dB);
        CONS8(gB, sB1, sB2, tB1, tB2);
        CONS8(hB, sB1, sB2, tB1, tB2);
      } else {
        CONS8(gB, sB1, sB2, tB1, tB2);
      }
    }
  }

  sA1 += tA1; sA2 += tA2; sB1 += tB1; sB2 += tB2;
  { float inv = __builtin_amdgcn_rcpf(fmaf(eaA, sA1, 1.0f));
    float lg = eaA * sA2 * inv;
    u16 hb = (u16)(selfA >> 16);
    float s_self = (float)(*(const _Float16*)&hb);
    _Float16 hs = (_Float16)(s_self * inv);
    u32 pk = (u32)f2bf(lg) | ((u32)(*(const u16*)&hs) << 16);
    lgsa[(size_t)(b * NNODE + nA) * 128 + h * 64 + c] = pk; }
  { float inv = __builtin_amdgcn_rcpf(fmaf(eaB, sB1, 1.0f));
    float lg = eaB * sB2 * inv;
    u16 hb = (u16)(selfB >> 16);
    float s_self = (float)(*(const _Float16*)&hb);
    _Float16 hs = (_Float16)(s_self * inv);
    u32 pk = (u32)f2bf(lg) | ((u32)(*(const u16*)&hs) << 16);
    lgsa[(size_t)(b * NNODE + nB) * 128 + h * 64 + c] = pk; }
}

// ---------------- host launcher ----------------------------------------------
extern "C" void kernel_launch(void* const* d_in, const int* in_sizes, int n_in,
                              void* d_out, int out_size, void* d_ws, size_t ws_size,
                              hipStream_t stream){
  (void)in_sizes; (void)n_in; (void)ws_size; (void)out_size;
  const void* objects = d_in[0];
  const void* Wo      = d_in[1];
  const void* Wa      = d_in[2];
  const void* Wla     = d_in[3];
  const void* attn_b  = d_in[4];
  const void* Wl      = d_in[5];
  const void* state_b = d_in[6];
  const int*  conn    = (const int*)d_in[7];

  char* base = (char*)d_ws;
  size_t off = 0;
  auto alloc = [&](size_t bytes) -> char* {
    char* p = base + off;
    off = (off + bytes + 255) & ~(size_t)255;
    return p;
  };
  int*      flag      = (int*)     alloc(256);
  u16*      Wt        = (u16*)     alloc((size_t)4 * 16384 * 2);
  float*    biasf     = (float*)   alloc(256 * 4);
  _Float16* eah       = (_Float16*)alloc((size_t)MROWS * 128 * 2);       // exp(aW) fp16
  u32*      gat0      = (u32*)     alloc((size_t)(MROWS + 4) * 64 * 4);  // ch 0-63 {S|EL} + 4 zero rows
  u32*      gat1      = (u32*)     alloc((size_t)(MROWS + 4) * 64 * 4);  // ch 64-127 + 4 zero rows
  u32*      lgsa      = (u32*)     alloc((size_t)MROWS * 128 * 4);       // {lg bf16 | sa fp16}
  u16*      partial   = (u16*)     alloc((size_t)BATCH * NCHUNK * PADN * 2);
  int*      row_start = (int*)     alloc((size_t)BATCH * (NNODE + 1) * 4);
  int*      edge_dst  = (int*)     alloc((size_t)BATCH * EDPAD * 4);     // padded CSR
  int*      deg       = (int*)     alloc((size_t)MROWS * 4);
  int*      bsum      = (int*)     alloc(160 * 4);

  prep_weights<<<257, 256, 0, stream>>>(objects, Wo, Wa, Wla, Wl, attn_b, state_b,
                                        flag, Wt, biasf);

  csr_hist<<<256, 256, 0, stream>>>(conn, partial);
  csr_colscan<<<160, 256, 0, stream>>>(partial, row_start, bsum, deg);
  scanC<<<160, 256, 0, stream>>>(row_start, bsum);
  csr_fill<<<256, 256, 0, stream>>>(conn, partial, row_start, edge_dst);
  pad_fill<<<160, 256, 0, stream>>>(row_start, deg, edge_dst, gat0, gat1);

  fused_init<<<MROWS / 32, 256, 0, stream>>>(objects, flag, Wt, biasf, eah, gat0, gat1);
  edge_kernel<<<MROWS / 2, 128, 0, stream>>>(eah, gat0, gat1, row_start, edge_dst, lgsa);
  fused_mid<<<MROWS / 32, 256, 0, stream>>>(lgsa, Wt, biasf, eah, gat0, gat1);
  edge_kernel<<<MROWS / 2, 128, 0, stream>>>(eah, gat0, gat1, row_start, edge_dst, lgsa);
  fused_mid<<<MROWS / 32, 256, 0, stream>>>(lgsa, Wt, biasf, eah, gat0, gat1);
  edge_kernel<<<MROWS / 2, 128, 0, stream>>>(eah, gat0, gat1, row_start, edge_dst, lgsa);
  final_out<<<MROWS / 32, 256, 0, stream>>>(lgsa, Wt, biasf, flag, d_out);
}

// Round 11
// 338.960 us; speedup vs baseline: 1.1594x; 1.0509x over previous
//
#include <hip/hip_runtime.h>
#include <hip/hip_bf16.h>

// AttentiveGraph: B=4, N=10000, E=160000, C=F=128, 3 iterations.
// R21: edge kernel confirmed at system floor (3 null MLP levers + 2 footprint
// regressions bracket it). Remaining ~235us = 10 serial small dispatches
// (avg ~24us each, compute content only a few us) -> serialization-bound.
// Collapse independent stages into block-range-partitioned kernels:
//   K1 = csr_hist [0,256) || prep_weights [256,513)      (independent)
//   K4 = fused_init [0,1250) || csr_fill [1250,1506) || pad_fill [1506,1666)
//        (init needs only K1 outputs; fill/pad write disjoint edge_dst
//         ranges; init's gat rows disjoint from pad's sentinel rows)
// 13 -> 10 dispatches; longest independent legs overlap instead of summing.
// Edge kernel (R20, verified), mids, final, colscan/scanC unchanged.

#define BATCH 4
#define NNODE 10000
#define NEDGE 160000
#define TWOE  (2*NEDGE)
#define MROWS (BATCH*NNODE)   // 40000
#define NCHUNK 64
#define CHUNKE (NEDGE/NCHUNK) // 2500
#define PADN  10240
#define EDPAD (TWOE + 8*NNODE) // 400000: padded edge capacity per batch

typedef unsigned short u16;
typedef unsigned int   u32;
typedef __attribute__((ext_vector_type(8))) short bf16x8_t;
typedef __attribute__((ext_vector_type(4))) float f32x4_t;

__device__ __forceinline__ float b2f(u16 h){ return __uint_as_float(((u32)h) << 16); }
__device__ __forceinline__ u16 f2bf(float f){
  u32 u = __float_as_uint(f);
  return (u16)((u + 0x7fffu + ((u >> 16) & 1u)) >> 16);   // RNE
}
__device__ __forceinline__ float fast_tanh(float x){
  float e = __expf(2.0f * x);
  return fmaf(-2.0f, __builtin_amdgcn_rcpf(e + 1.0f), 1.0f);
}

__device__ __forceinline__ void chunk_of(int blk, int& b, int& c){
  int xcd = blk & 7;
  b = xcd >> 1;
  c = ((blk >> 3) << 1) | (xcd & 1);           // 0..63
}

// ---------------- K1: csr_hist [0,256) || prep_weights [256,513) --------------
__global__ void __launch_bounds__(256) k1_prep_hist(const int* __restrict__ conn,
    u16* __restrict__ partial,
    const void* __restrict__ objects,
    const void* __restrict__ Wo, const void* __restrict__ Wa,
    const void* __restrict__ Wla, const void* __restrict__ Wl,
    const void* __restrict__ ab, const void* __restrict__ sb,
    int* __restrict__ flag, u16* __restrict__ Wt, float* __restrict__ biasf){
  __shared__ u32 hist[NNODE];
  __shared__ int zc, hc;
  if (blockIdx.x < 256){
    // ---- csr_hist ----
    int b, c; chunk_of(blockIdx.x, b, c);
    for (int n = threadIdx.x; n < NNODE; n += 256) hist[n] = 0;
    __syncthreads();
    const int2* cp = (const int2*)conn + (size_t)b * NEDGE + c * CHUNKE;
    for (int i = threadIdx.x; i < CHUNKE; i += 256){
      int2 e = cp[i];
      atomicAdd(&hist[e.x], 1);
      atomicAdd(&hist[e.y], 1);
    }
    __syncthreads();
    u16* prow = partial + (size_t)(b * NCHUNK + c) * PADN;
    for (int n = threadIdx.x; n < NNODE; n += 256) prow[n] = (u16)hist[n];
  } else {
    // ---- prep_weights (with fused dtype probe) ----
    if (threadIdx.x == 0){ zc = 0; hc = 0; }
    __syncthreads();
    const u32* objw = (const u32*)objects;
    int z = 0, hcnt = 0;
    for (int i = threadIdx.x; i < 1024; i += 256){
      u32 lo = objw[i] & 0xffffu;
      if (lo == 0) z++;
      if (((lo >> 7) & 0xffu) >= 160u) hcnt++;
    }
    atomicAdd(&zc, z); atomicAdd(&hc, hcnt);
    __syncthreads();
    bool f = (hc > 0 || zc > 512);              // 1 = fp32 storage
    int p = blockIdx.x - 256;
    if (p == 0 && threadIdx.x == 0) *flag = f ? 1 : 0;
    int idx = p * 256 + threadIdx.x;
    if (idx < 65536){
      int m = idx >> 14, k = (idx >> 7) & 127, c = idx & 127;
      const void* src = (m == 0) ? Wo : (m == 1) ? Wa : (m == 2) ? Wla : Wl;
      u16 h = f ? f2bf(((const float*)src)[k * 128 + c]) : ((const u16*)src)[k * 128 + c];
      Wt[m * 16384 + c * 128 + k] = h;
    } else {
      int t = idx - 65536;
      const void* src = (t < 128) ? sb : ab;
      int i = t & 127;
      biasf[t] = f ? ((const float*)src)[i] : b2f(((const u16*)src)[i]);
    }
  }
}

// ---------------- CSR scans (unchanged) ---------------------------------------
__global__ void __launch_bounds__(256) csr_colscan(u16* __restrict__ partial,
    int* __restrict__ row_start, int* __restrict__ bsum, int* __restrict__ deg){
  int b = blockIdx.x / 40, w = blockIdx.x % 40;
  int n = w * 256 + threadIdx.x;
  u32 run = 0;
  if (n < NNODE){
    #pragma unroll 8
    for (int c = 0; c < NCHUNK; c++){
      size_t idx = (size_t)(b * NCHUNK + c) * PADN + n;
      u32 v = partial[idx];
      partial[idx] = (u16)run;
      run += v;
    }
  }
  u32 pad = (run + 7u) & ~7u;
  __shared__ u32 buf[256];
  buf[threadIdx.x] = pad;
  __syncthreads();
  for (int off = 1; off < 256; off <<= 1){
    u32 x = (threadIdx.x >= (unsigned)off) ? buf[threadIdx.x - off] : 0;
    __syncthreads();
    buf[threadIdx.x] += x;
    __syncthreads();
  }
  u32 incl = buf[threadIdx.x];
  if (n < NNODE){
    row_start[b * (NNODE + 1) + n] = (int)(incl - pad);  // window-local padded
    deg[b * NNODE + n] = (int)run;
  }
  if (threadIdx.x == 255) bsum[blockIdx.x] = (int)incl;
}

__global__ void scanC(int* __restrict__ row_start, const int* __restrict__ bsum){
  int b = blockIdx.x / 40, j = blockIdx.x % 40;
  int n = j * 256 + threadIdx.x;
  int off = 0;
  for (int q = b * 40; q < b * 40 + j; q++) off += bsum[q];
  if (n < NNODE) row_start[b * (NNODE + 1) + n] += off;
  if (j == 39 && threadIdx.x == 0)
    row_start[b * (NNODE + 1) + NNODE] = off + bsum[b * 40 + 39];
}

// ---------------- MFMA helpers (wave = 16 rows x 64 cols) ---------------------
__device__ __forceinline__ void gemm_tile4(const u16* __restrict__ arow,
    const u16* __restrict__ wt, int lm, int lq, int cofs, f32x4_t acc[4]){
  #pragma unroll
  for (int ks = 0; ks < 4; ks++){
    bf16x8_t a = *(const bf16x8_t*)(arow + ks * 32);
    #pragma unroll
    for (int nb = 0; nb < 4; nb++){
      bf16x8_t bfr = *(const bf16x8_t*)(wt + (cofs + nb * 16 + lm) * 128 + ks * 32 + lq * 8);
      acc[nb] = __builtin_amdgcn_mfma_f32_16x16x32_bf16(a, bfr, acc[nb], 0, 0, 0);
    }
  }
}

__device__ __forceinline__ void gemm_tile4_packed(const u32* __restrict__ Lrow,
    const u16* __restrict__ wt, int lm, int lq, int cofs, f32x4_t acc[4]){
  #pragma unroll
  for (int ks = 0; ks < 4; ks++){
    uint4 wa = *(const uint4*)(Lrow + ks * 32 + lq * 8);
    uint4 wb = *(const uint4*)(Lrow + ks * 32 + lq * 8 + 4);
    bf16x8_t a;
    a[0] = (short)wa.x; a[1] = (short)wa.y; a[2] = (short)wa.z; a[3] = (short)wa.w;
    a[4] = (short)wb.x; a[5] = (short)wb.y; a[6] = (short)wb.z; a[7] = (short)wb.w;
    #pragma unroll
    for (int nb = 0; nb < 4; nb++){
      bf16x8_t bfr = *(const bf16x8_t*)(wt + (cofs + nb * 16 + lm) * 128 + ks * 32 + lq * 8);
      acc[nb] = __builtin_amdgcn_mfma_f32_16x16x32_bf16(a, bfr, acc[nb], 0, 0, 0);
    }
  }
}

// phase 2: states tile (LDS, pointer-based) -> gat {S fp16 hi | EL fp16 lo}
// u32 stores + ea fp16 into eat tile.
__device__ __forceinline__ void phase2_awlaw4(const u16* __restrict__ ldstile,
    const u16* __restrict__ Wt, const float* __restrict__ biasf,
    int lm, int lq, int cofs, int r0, _Float16* __restrict__ eat,
    u32* __restrict__ ghw){
  const u16* Wta  = Wt + 16384;
  const u16* Wtla = Wt + 32768;
  const u16* ldsrow = ldstile + lm * 136 + lq * 8;
  f32x4_t accA[4], accL[4];
  #pragma unroll
  for (int i = 0; i < 4; i++){ accA[i] = (f32x4_t){0.f,0.f,0.f,0.f}; accL[i] = (f32x4_t){0.f,0.f,0.f,0.f}; }
  #pragma unroll
  for (int ks = 0; ks < 4; ks++){
    bf16x8_t a = *(const bf16x8_t*)(ldsrow + ks * 32);
    #pragma unroll
    for (int nb = 0; nb < 4; nb++){
      bf16x8_t ba = *(const bf16x8_t*)(Wta  + (cofs + nb * 16 + lm) * 128 + ks * 32 + lq * 8);
      bf16x8_t bl = *(const bf16x8_t*)(Wtla + (cofs + nb * 16 + lm) * 128 + ks * 32 + lq * 8);
      accA[nb] = __builtin_amdgcn_mfma_f32_16x16x32_bf16(a, ba, accA[nb], 0, 0, 0);
      accL[nb] = __builtin_amdgcn_mfma_f32_16x16x32_bf16(a, bl, accL[nb], 0, 0, 0);
    }
  }
  #pragma unroll
  for (int nb = 0; nb < 4; nb++){
    int col = cofs + nb * 16 + lm;
    float bb = biasf[128 + col];
    #pragma unroll
    for (int i = 0; i < 4; i++){
      int row = r0 + lq * 4 + i;
      float ea = fminf(__expf(accA[nb][i]), 60000.0f);   // fp16-safe
      eat[(lq * 4 + i) * 128 + col] = (_Float16)ea;
      _Float16 elh = (_Float16)fminf(__expf(accL[nb][i] + bb), 60000.0f);
      u16 sbf = ldstile[(lq * 4 + i) * 136 + col];
      _Float16 sh = (_Float16)b2f(sbf);                  // bf16 -> fp16 exact
      u32 elu = (u32)(*(const u16*)&elh);
      u32 shu = (u32)(*(const u16*)&sh);
      ghw[(size_t)row * 64 + (col & 63)] = elu | (shu << 16);
    }
  }
}

// coalesced eah writeback: 2 tiles x 16 rows x 128 fp16 = 8KB, 16B/thread x2.
__device__ __forceinline__ void eah_writeback(const _Float16* __restrict__ eat,
    _Float16* __restrict__ eah, int blk_r0, int tid){
  const uint4* src = (const uint4*)eat;       // 512 x 16B
  uint4* dst = (uint4*)(eah + (size_t)blk_r0 * 128);
  dst[tid]       = src[tid];
  dst[tid + 256] = src[tid + 256];
}

// init body (pointer-based shared), shared by K4.
__device__ __forceinline__ void fused_init_body(int blk, int tid,
    const void* __restrict__ obj_raw, const int* __restrict__ flag,
    const u16* __restrict__ Wt, const float* __restrict__ biasf,
    _Float16* __restrict__ eah, u32* __restrict__ gat0, u32* __restrict__ gat1,
    u16* __restrict__ lds, _Float16* __restrict__ eat){
  const int lane = tid & 63, wave = tid >> 6;
  const int t = wave >> 1, ch = wave & 1, cofs = ch * 64;
  const int r0 = blk * 32 + t * 16;
  const int lm = lane & 15, lq = lane >> 4;
  u16* ldsT = lds + t * 2176;                  // 16*136
  _Float16* eatT = eat + t * 2048;             // 16*128
  f32x4_t acc[4];
  #pragma unroll
  for (int i = 0; i < 4; i++) acc[i] = (f32x4_t){0.f, 0.f, 0.f, 0.f};
  if (*flag){
    const float* arow = (const float*)obj_raw + (size_t)(r0 + lm) * 128 + lq * 8;
    #pragma unroll
    for (int ks = 0; ks < 4; ks++){
      float4 fa = *(const float4*)(arow + ks * 32);
      float4 fb = *(const float4*)(arow + ks * 32 + 4);
      bf16x8_t a;
      a[0] = (short)f2bf(fa.x); a[1] = (short)f2bf(fa.y);
      a[2] = (short)f2bf(fa.z); a[3] = (short)f2bf(fa.w);
      a[4] = (short)f2bf(fb.x); a[5] = (short)f2bf(fb.y);
      a[6] = (short)f2bf(fb.z); a[7] = (short)f2bf(fb.w);
      #pragma unroll
      for (int nb = 0; nb < 4; nb++){
        bf16x8_t bfr = *(const bf16x8_t*)(Wt + (cofs + nb * 16 + lm) * 128 + ks * 32 + lq * 8);
        acc[nb] = __builtin_amdgcn_mfma_f32_16x16x32_bf16(a, bfr, acc[nb], 0, 0, 0);
      }
    }
  } else {
    gemm_tile4((const u16*)obj_raw + (size_t)(r0 + lm) * 128 + lq * 8, Wt, lm, lq, cofs, acc);
  }
  #pragma unroll
  for (int nb = 0; nb < 4; nb++){
    int col = cofs + nb * 16 + lm;
    float bb = biasf[col];
    #pragma unroll
    for (int i = 0; i < 4; i++)
      ldsT[(lq * 4 + i) * 136 + col] = f2bf(fast_tanh(acc[nb][i] + bb));
  }
  __syncthreads();
  phase2_awlaw4(ldsT, Wt, biasf, lm, lq, cofs, r0, eatT, ch ? gat1 : gat0);
  __syncthreads();
  eah_writeback(eat, eah, blk * 32, tid);
}

// ---------------- K4: fused_init || csr_fill || pad_fill ----------------------
__global__ void __launch_bounds__(256) k4_init_fill_pad(
    const void* __restrict__ obj_raw, const int* __restrict__ flag,
    const u16* __restrict__ Wt, const float* __restrict__ biasf,
    _Float16* __restrict__ eah, u32* __restrict__ gat0, u32* __restrict__ gat1,
    const int* __restrict__ conn, const u16* __restrict__ partial,
    const int* __restrict__ row_start, int* __restrict__ edge_dst,
    const int* __restrict__ deg){
  __shared__ __align__(16) char smem[40960];
  int blk = blockIdx.x;
  if (blk < 1250){
    // ---- fused_init ----
    u16* lds = (u16*)smem;                       // 8704B
    _Float16* eat = (_Float16*)(smem + 8704);    // 8192B
    fused_init_body(blk, (int)threadIdx.x, obj_raw, flag, Wt, biasf,
                    eah, gat0, gat1, lds, eat);
  } else if (blk < 1506){
    // ---- csr_fill ----
    int b, c; chunk_of(blk - 1250, b, c);
    u32* cur = (u32*)smem;                       // 40000B
    const u16* prow = partial + (size_t)(b * NCHUNK + c) * PADN;
    const int* rs = row_start + b * (NNODE + 1);
    for (int n = threadIdx.x; n < NNODE; n += 256) cur[n] = (u32)rs[n] + prow[n];
    __syncthreads();
    const int2* cp = (const int2*)conn + (size_t)b * NEDGE + c * CHUNKE;
    int* edb = edge_dst + (size_t)b * EDPAD;
    for (int i = threadIdx.x; i < CHUNKE; i += 256){
      int2 e = cp[i];
      u32 p1 = atomicAdd(&cur[e.x], 1); edb[p1] = e.y;
      u32 p2 = atomicAdd(&cur[e.y], 1); edb[p2] = e.x;
    }
  } else {
    // ---- pad_fill (+ sentinel gat rows + batch tail fill) ----
    int p = blk - 1506;
    if (p == 0){
      size_t base = (size_t)MROWS * 64;
      gat0[base + threadIdx.x] = 0;
      gat1[base + threadIdx.x] = 0;
    }
    int b = p / 40, j = p % 40;
    const int* rs = row_start + b * (NNODE + 1);
    int sent = 40000 - 9999 * b;   // local d -> global gat row 40000+b (zero)
    int* edb = edge_dst + (size_t)b * EDPAD;
    if (j == 0){                    // fill uninitialized batch tail
      int T = rs[NNODE];
      for (int q = T + (int)threadIdx.x; q < EDPAD; q += 256) edb[q] = sent;
    }
    int n = j * 256 + threadIdx.x;
    if (n < NNODE){
      int s = rs[n] + deg[b * NNODE + n];
      int epad = rs[n + 1];
      for (int q = s; q < epad; q++) edb[q] = sent;
    }
  }
}

// mid: states = tanh(sa + lg@Wl + b); then eah/EL/S for next iter.
__global__ void __launch_bounds__(256) fused_mid(const u32* __restrict__ lgsa,
    const u16* __restrict__ Wt, const float* __restrict__ biasf,
    _Float16* __restrict__ eah, u32* __restrict__ gat0, u32* __restrict__ gat1){
  __shared__ u16 lds[2][16 * 136];
  __shared__ _Float16 eat[2][16 * 128];
  const int lane = threadIdx.x & 63, wave = threadIdx.x >> 6;
  const int t = wave >> 1, ch = wave & 1, cofs = ch * 64;
  const int r0 = blockIdx.x * 32 + t * 16;
  const int lm = lane & 15, lq = lane >> 4;
  f32x4_t acc[4];
  #pragma unroll
  for (int i = 0; i < 4; i++) acc[i] = (f32x4_t){0.f, 0.f, 0.f, 0.f};
  gemm_tile4_packed(lgsa + (size_t)(r0 + lm) * 128, Wt + 49152, lm, lq, cofs, acc);
  #pragma unroll
  for (int nb = 0; nb < 4; nb++){
    int col = cofs + nb * 16 + lm;
    float bb = biasf[col];
    #pragma unroll
    for (int i = 0; i < 4; i++){
      int row = r0 + lq * 4 + i;
      u32 v = lgsa[(size_t)row * 128 + col];
      u16 hb = (u16)(v >> 16);
      float sa = (float)(*(const _Float16*)&hb);
      lds[t][(lq * 4 + i) * 136 + col] = f2bf(fast_tanh(sa + acc[nb][i] + bb));
    }
  }
  __syncthreads();
  phase2_awlaw4(&lds[t][0], Wt, biasf, lm, lq, cofs, r0, &eat[t][0], ch ? gat1 : gat0);
  __syncthreads();
  eah_writeback(&eat[0][0], eah, blockIdx.x * 32, threadIdx.x);
}

// final: out = tanh(sa + lg@Wl + b), fp32 or bf16 per flag.
__global__ void __launch_bounds__(256) final_out(const u32* __restrict__ lgsa,
    const u16* __restrict__ Wt, const float* __restrict__ biasf,
    const int* __restrict__ flag, void* __restrict__ outp){
  const int lane = threadIdx.x & 63, wave = threadIdx.x >> 6;
  const int t = wave >> 1, ch = wave & 1, cofs = ch * 64;
  const int r0 = blockIdx.x * 32 + t * 16;
  const int lm = lane & 15, lq = lane >> 4;
  bool f32out = (*flag != 0);
  f32x4_t acc[4];
  #pragma unroll
  for (int i = 0; i < 4; i++) acc[i] = (f32x4_t){0.f, 0.f, 0.f, 0.f};
  gemm_tile4_packed(lgsa + (size_t)(r0 + lm) * 128, Wt + 49152, lm, lq, cofs, acc);
  #pragma unroll
  for (int nb = 0; nb < 4; nb++){
    int col = cofs + nb * 16 + lm;
    float bb = biasf[col];
    #pragma unroll
    for (int i = 0; i < 4; i++){
      int row = r0 + lq * 4 + i;
      u32 vv = lgsa[(size_t)row * 128 + col];
      u16 hb = (u16)(vv >> 16);
      float sa = (float)(*(const _Float16*)&hb);
      float v = fast_tanh(sa + acc[nb][i] + bb);
      if (f32out) ((float*)outp)[(size_t)row * 128 + col] = v;
      else        ((u16*)  outp)[(size_t)row * 128 + col] = f2bf(v);
    }
  }
}

// ---------------- edge gather: 2 node-chains per wave (R20, verified) ---------
__device__ __forceinline__ void acc_mix(u32 g, float one, float& a1, float& a2){
  asm("v_fma_mix_f32 %0, %2, %3, %0 op_sel:[0,0,0] op_sel_hi:[1,0,0]\n\t"
      "v_fma_mix_f32 %1, %2, %2, %1 op_sel:[0,1,0] op_sel_hi:[1,1,0]"
      : "+v"(a1), "+v"(a2)
      : "v"(g), "v"(one));
}

__device__ __forceinline__ u32 gath1(const u32* __restrict__ gh, int d, int c){
  const u32* p = (const u32*)((const char*)gh + ((size_t)(u32)d << 8));
  return p[c];
}

#define LDIDX(d, p) { const int* ep_ = (p); _Pragma("unroll") \
  for (int j = 0; j < 8; j++) d[j] = __builtin_amdgcn_readfirstlane(ep_[j]); }
#define GATH8(g, d) { _Pragma("unroll") \
  for (int j = 0; j < 8; j++) g[j] = gath1(gh, d[j], c); }
#define CONS8(g, s1, s2, t1, t2) { _Pragma("unroll") \
  for (int j = 0; j < 8; j++) acc_mix(g[j], one, (j & 1) ? t1 : s1, (j & 1) ? t2 : s2); }

__global__ void __launch_bounds__(128, 6) edge_kernel(const _Float16* __restrict__ eah,
    const u32* __restrict__ gat0, const u32* __restrict__ gat1,
    const int* __restrict__ row_start, const int* __restrict__ edge_dst,
    u32* __restrict__ lgsa){
  int blk = blockIdx.x;
  int xcd = blk & 7;
  int b = xcd >> 1, h = xcd & 1;
  int i = blk >> 3;                          // 0..2499
  int w = (int)(threadIdx.x >> 6);
  int nA = i * 4 + w * 2, nB = nA + 1;
  int c = threadIdx.x & 63;
  const u32* gh = (h ? gat1 : gat0) + (size_t)b * NNODE * 64;
  const int* rs = row_start + b * (NNODE + 1);
  int eA  = __builtin_amdgcn_readfirstlane(rs[nA]);
  int eA1 = __builtin_amdgcn_readfirstlane(rs[nA + 1]);
  int eB1 = __builtin_amdgcn_readfirstlane(rs[nB + 1]);
  int eB = eA1;
  const int* ed = edge_dst + (size_t)b * EDPAD;

  float eaA = (float)eah[(size_t)(b * NNODE + nA) * 128 + h * 64 + c];
  float eaB = (float)eah[(size_t)(b * NNODE + nB) * 128 + h * 64 + c];
  u32 selfA = gh[((size_t)nA << 6) + c];
  u32 selfB = gh[((size_t)nB << 6) + c];
  const float one = 1.0f;

  float sA1=0.f, sA2=0.f, tA1=0.f, tA2=0.f;
  float sB1=0.f, sB2=0.f, tB1=0.f, tB2=0.f;
  int ngA = (eA1 - eA) >> 3, ngB = (eB1 - eB) >> 3;  // rows padded: len%8==0
  int dA[8], dB[8]; u32 gA[8], gB[8], hA[8], hB[8];

  if (ngA){ LDIDX(dA, ed + eA); }
  if (ngB){ LDIDX(dB, ed + eB); }
  if (ngA){ GATH8(gA, dA); eA += 8; LDIDX(dA, ed + eA); }
  if (ngB){ GATH8(gB, dB); eB += 8; LDIDX(dB, ed + eB); }

  int m = ngA < ngB ? ngA : ngB;
  int cons = 0;
  for (; cons + 2 <= m; cons += 2){
    GATH8(hA, dA); eA += 8; LDIDX(dA, ed + eA);
    GATH8(hB, dB); eB += 8; LDIDX(dB, ed + eB);
    CONS8(gA, sA1, sA2, tA1, tA2);
    CONS8(gB, sB1, sB2, tB1, tB2);
    GATH8(gA, dA); eA += 8; LDIDX(dA, ed + eA);
    GATH8(gB, dB); eB += 8; LDIDX(dB, ed + eB);
    CONS8(hA, sA1, sA2, tA1, tA2);
    CONS8(hB, sB1, sB2, tB1, tB2);
  }

  { int rem = ngA - cons;
    if (rem > 0){
      int k = 1;
      for (; k + 1 < rem; k += 2){
        GATH8(hA, dA); eA += 8; LDIDX(dA, ed + eA);
        CONS8(gA, sA1, sA2, tA1, tA2);
        GATH8(gA, dA); eA += 8; LDIDX(dA, ed + eA);
        CONS8(hA, sA1, sA2, tA1, tA2);
      }
      if (k < rem){
        GATH8(hA, dA);
        CONS8(gA, sA1, sA2, tA1, tA2);
        CONS8(hA, sA1, sA2, tA1, tA2);
      } else {
        CONS8(gA, sA1, sA2, tA1, tA2);
      }
    }
  }
  { int rem = ngB - cons;
    if (rem > 0){
      int k = 1;
      for (; k + 1 < rem; k += 2){
        GATH8(hB, dB); eB += 8; LDIDX(dB, ed + eB);
        CONS8(gB, sB1, sB2, tB1, tB2);
        GATH8(gB, dB); eB += 8; LDIDX(dB, ed + eB);
        CONS8(hB, sB1, sB2, tB1, tB2);
      }
      if (k < rem){
        GATH8(hB, dB);
        CONS8(gB, sB1, sB2, tB1, tB2);
        CONS8(hB, sB1, sB2, tB1, tB2);
      } else {
        CONS8(gB, sB1, sB2, tB1, tB2);
      }
    }
  }

  sA1 += tA1; sA2 += tA2; sB1 += tB1; sB2 += tB2;
  { float inv = __builtin_amdgcn_rcpf(fmaf(eaA, sA1, 1.0f));
    float lg = eaA * sA2 * inv;
    u16 hb = (u16)(selfA >> 16);
    float s_self = (float)(*(const _Float16*)&hb);
    _Float16 hs = (_Float16)(s_self * inv);
    u32 pk = (u32)f2bf(lg) | ((u32)(*(const u16*)&hs) << 16);
    lgsa[(size_t)(b * NNODE + nA) * 128 + h * 64 + c] = pk; }
  { float inv = __builtin_amdgcn_rcpf(fmaf(eaB, sB1, 1.0f));
    float lg = eaB * sB2 * inv;
    u16 hb = (u16)(selfB >> 16);
    float s_self = (float)(*(const _Float16*)&hb);
    _Float16 hs = (_Float16)(s_self * inv);
    u32 pk = (u32)f2bf(lg) | ((u32)(*(const u16*)&hs) << 16);
    lgsa[(size_t)(b * NNODE + nB) * 128 + h * 64 + c] = pk; }
}

// ---------------- host launcher ----------------------------------------------
extern "C" void kernel_launch(void* const* d_in, const int* in_sizes, int n_in,
                              void* d_out, int out_size, void* d_ws, size_t ws_size,
                              hipStream_t stream){
  (void)in_sizes; (void)n_in; (void)ws_size; (void)out_size;
  const void* objects = d_in[0];
  const void* Wo      = d_in[1];
  const void* Wa      = d_in[2];
  const void* Wla     = d_in[3];
  const void* attn_b  = d_in[4];
  const void* Wl      = d_in[5];
  const void* state_b = d_in[6];
  const int*  conn    = (const int*)d_in[7];

  char* base = (char*)d_ws;
  size_t off = 0;
  auto alloc = [&](size_t bytes) -> char* {
    char* p = base + off;
    off = (off + bytes + 255) & ~(size_t)255;
    return p;
  };
  int*      flag      = (int*)     alloc(256);
  u16*      Wt        = (u16*)     alloc((size_t)4 * 16384 * 2);
  float*    biasf     = (float*)   alloc(256 * 4);
  _Float16* eah       = (_Float16*)alloc((size_t)MROWS * 128 * 2);       // exp(aW) fp16
  u32*      gat0      = (u32*)     alloc((size_t)(MROWS + 4) * 64 * 4);  // ch 0-63 {S|EL} + 4 zero rows
  u32*      gat1      = (u32*)     alloc((size_t)(MROWS + 4) * 64 * 4);  // ch 64-127 + 4 zero rows
  u32*      lgsa      = (u32*)     alloc((size_t)MROWS * 128 * 4);       // {lg bf16 | sa fp16}
  u16*      partial   = (u16*)     alloc((size_t)BATCH * NCHUNK * PADN * 2);
  int*      row_start = (int*)     alloc((size_t)BATCH * (NNODE + 1) * 4);
  int*      edge_dst  = (int*)     alloc((size_t)BATCH * EDPAD * 4);     // padded CSR
  int*      deg       = (int*)     alloc((size_t)MROWS * 4);
  int*      bsum      = (int*)     alloc(160 * 4);

  k1_prep_hist<<<513, 256, 0, stream>>>(conn, partial, objects, Wo, Wa, Wla, Wl,
                                        attn_b, state_b, flag, Wt, biasf);
  csr_colscan<<<160, 256, 0, stream>>>(partial, row_start, bsum, deg);
  scanC<<<160, 256, 0, stream>>>(row_start, bsum);
  k4_init_fill_pad<<<1666, 256, 0, stream>>>(objects, flag, Wt, biasf, eah,
                                             gat0, gat1, conn, partial,
                                             row_start, edge_dst, deg);

  edge_kernel<<<MROWS / 2, 128, 0, stream>>>(eah, gat0, gat1, row_start, edge_dst, lgsa);
  fused_mid<<<MROWS / 32, 256, 0, stream>>>(lgsa, Wt, biasf, eah, gat0, gat1);
  edge_kernel<<<MROWS / 2, 128, 0, stream>>>(eah, gat0, gat1, row_start, edge_dst, lgsa);
  fused_mid<<<MROWS / 32, 256, 0, stream>>>(lgsa, Wt, biasf, eah, gat0, gat1);
  edge_kernel<<<MROWS / 2, 128, 0, stream>>>(eah, gat0, gat1, row_start, edge_dst, lgsa);
  final_out<<<MROWS / 32, 256, 0, stream>>>(lgsa, Wt, biasf, flag, d_out);
}